// Round 1
// 651.218 us; speedup vs baseline: 1.1989x; 1.1989x over previous
//
#include <hip/hip_runtime.h>

#define NN 100000
#define NE 600000
#define DD 128
#define NL 4
#define GB 512  // persistent GEMM grid: 2 blocks/CU x 256 CU

typedef __attribute__((ext_vector_type(8))) short short8;
typedef __attribute__((ext_vector_type(4))) float float4v;

__device__ inline unsigned short f2bf(float f) {
  union { float f; unsigned u; } v; v.f = f;
  unsigned r = v.u + 0x7fff + ((v.u >> 16) & 1);  // round-to-nearest-even
  return (unsigned short)(r >> 16);
}
__device__ inline float bf2f(unsigned short u) {
  union { unsigned u; float f; } v; v.u = ((unsigned)u) << 16;
  return v.f;
}

// ---------------- utility ----------------
__global__ void k_zero_i(int* p, int n) {
  int i = blockIdx.x * 256 + threadIdx.x;
  if (i < n) p[i] = 0;
}
__global__ void k_zero_f(float* p, int n) {
  int i = blockIdx.x * 256 + threadIdx.x;
  if (i < n) p[i] = 0.f;
}
// fp32 [NN,128] -> bf16 mirror (layer-0 gather payload only; later layers fused in gemm2)
__global__ void k_h2b(const float* __restrict__ src, unsigned short* __restrict__ dst) {
  int i = blockIdx.x * 256 + threadIdx.x;
  if (i >= NN * DD / 4) return;
  float4 v = ((const float4*)src)[i];
  ushort4 o;
  o.x = f2bf(v.x); o.y = f2bf(v.y); o.z = f2bf(v.z); o.w = f2bf(v.w);
  ((ushort4*)dst)[i] = o;
}

// ---------------- one-time: W1/W2 -> bf16, transposed [n][k] ----------------
__global__ void k_prep(const float* __restrict__ W1, const float* __restrict__ W2,
                       unsigned short* __restrict__ WT) {
  int i = blockIdx.x * 256 + threadIdx.x;  // over 8*16384
  if (i >= 8 * 16384) return;
  int m = i >> 14;
  int el = i & 16383;
  int k = el >> 7;
  int n = el & 127;
  const float* src = (m < 4) ? (W1 + (size_t)m * 16384) : (W2 + (size_t)(m - 4) * 16384);
  WT[(size_t)m * 16384 + n * 128 + k] = f2bf(src[k * 128 + n]);
}

// ---------------- CSR build (once per call) ----------------
__global__ void k_count(const int* __restrict__ ei, int* __restrict__ counts) {
  int e = blockIdx.x * 256 + threadIdx.x;
  if (e < NE) atomicAdd(&counts[ei[NE + e]], 1);
}

#define ST 256
#define SC 2
#define SB ((NN + ST * SC - 1) / (ST * SC))  // 196 blocks

__global__ void k_scan_part(const int* __restrict__ counts, int* __restrict__ row_ptr,
                            int* __restrict__ bsums) {
  __shared__ int s[ST];
  int b = blockIdx.x, t = threadIdx.x;
  int base = b * (ST * SC) + t * SC;
  int v0 = (base < NN) ? counts[base] : 0;
  int v1 = (base + 1 < NN) ? counts[base + 1] : 0;
  int tsum = v0 + v1;
  s[t] = tsum;
  __syncthreads();
  for (int d = 1; d < ST; d <<= 1) {
    int x = (t >= d) ? s[t - d] : 0;
    __syncthreads();
    s[t] += x;
    __syncthreads();
  }
  int excl = s[t] - tsum;
  if (base < NN) row_ptr[base] = excl;
  if (base + 1 < NN) row_ptr[base + 1] = excl + v0;
  if (t == ST - 1) bsums[b] = s[t];
}

__global__ void k_scan_bsum(const int* __restrict__ bsums, int* __restrict__ boffs,
                            int* __restrict__ row_ptr) {
  __shared__ int s[ST];
  int t = threadIdx.x;
  int v = (t < SB) ? bsums[t] : 0;
  s[t] = v;
  __syncthreads();
  for (int d = 1; d < ST; d <<= 1) {
    int x = (t >= d) ? s[t - d] : 0;
    __syncthreads();
    s[t] += x;
    __syncthreads();
  }
  if (t < SB) boffs[t] = s[t] - v;
  if (t == ST - 1) row_ptr[NN] = s[t];
}

__global__ void k_scan_add(const int* __restrict__ boffs, int* __restrict__ row_ptr,
                           int* __restrict__ off) {
  int b = blockIdx.x, t = threadIdx.x;
  int base = b * (ST * SC) + t * SC;
  int o = boffs[b];
  if (base < NN) { row_ptr[base] += o; off[base] = 0; }
  if (base + 1 < NN) { row_ptr[base + 1] += o; off[base + 1] = 0; }
}

__global__ void k_fill(const int* __restrict__ ei, const float* __restrict__ attr,
                       const int* __restrict__ row_ptr, int* __restrict__ off,
                       int* __restrict__ csr_src, float* __restrict__ csr_attr) {
  int e = blockIdx.x * 256 + threadIdx.x;
  if (e >= NE) return;
  int srcv = ei[e];
  int dstv = ei[NE + e];
  int pos = atomicAdd(&off[dstv], 1);
  int idx = row_ptr[dstv] + pos;
  csr_src[idx] = srcv;
  csr_attr[idx] = attr[e];
}

// ------- aggregation: zb = bf16( (1+eps)*h + sum relu(hb[src]+attr*We+be) ) -------
// (bf16 output is numerically identical to old path: gemm0 staged f2bf(z) anyway.)
__global__ void k_agg(const float* __restrict__ h, const unsigned short* __restrict__ hb,
                      const int* __restrict__ row_ptr,
                      const int* __restrict__ csr_src, const float* __restrict__ csr_attr,
                      const float* __restrict__ We, const float* __restrict__ be,
                      const float* __restrict__ epsp, unsigned short* __restrict__ zb) {
  int gid = blockIdx.x * blockDim.x + threadIdx.x;
  int n = gid >> 6;
  int lane = gid & 63;
  if (n >= NN) return;
  int d0 = lane * 2;
  float we0 = We[d0], we1 = We[d0 + 1];
  float be0 = be[d0], be1 = be[d0 + 1];
  int b = row_ptr[n], e = row_ptr[n + 1];
  int deg = e - b;
  int cnt = (deg < 64) ? deg : 64;
  int myidx = (lane < cnt) ? csr_src[b + lane] : 0;
  float myatt = (lane < cnt) ? csr_attr[b + lane] : 0.f;
  float acc0 = 0.f, acc1 = 0.f;
  int i = 0;
  for (; i + 4 <= cnt; i += 4) {
    int s0 = __shfl(myidx, i);
    int s1 = __shfl(myidx, i + 1);
    int s2 = __shfl(myidx, i + 2);
    int s3 = __shfl(myidx, i + 3);
    float a0 = __shfl(myatt, i);
    float a1 = __shfl(myatt, i + 1);
    float a2 = __shfl(myatt, i + 2);
    float a3 = __shfl(myatt, i + 3);
    unsigned hv0 = *(const unsigned*)(hb + (size_t)s0 * DD + d0);
    unsigned hv1 = *(const unsigned*)(hb + (size_t)s1 * DD + d0);
    unsigned hv2 = *(const unsigned*)(hb + (size_t)s2 * DD + d0);
    unsigned hv3 = *(const unsigned*)(hb + (size_t)s3 * DD + d0);
    acc0 += fmaxf(bf2f((unsigned short)(hv0 & 0xffffu)) + fmaf(a0, we0, be0), 0.f);
    acc1 += fmaxf(bf2f((unsigned short)(hv0 >> 16)) + fmaf(a0, we1, be1), 0.f);
    acc0 += fmaxf(bf2f((unsigned short)(hv1 & 0xffffu)) + fmaf(a1, we0, be0), 0.f);
    acc1 += fmaxf(bf2f((unsigned short)(hv1 >> 16)) + fmaf(a1, we1, be1), 0.f);
    acc0 += fmaxf(bf2f((unsigned short)(hv2 & 0xffffu)) + fmaf(a2, we0, be0), 0.f);
    acc1 += fmaxf(bf2f((unsigned short)(hv2 >> 16)) + fmaf(a2, we1, be1), 0.f);
    acc0 += fmaxf(bf2f((unsigned short)(hv3 & 0xffffu)) + fmaf(a3, we0, be0), 0.f);
    acc1 += fmaxf(bf2f((unsigned short)(hv3 >> 16)) + fmaf(a3, we1, be1), 0.f);
  }
  for (; i < cnt; i++) {
    int s = __shfl(myidx, i);
    float a = __shfl(myatt, i);
    unsigned hv = *(const unsigned*)(hb + (size_t)s * DD + d0);
    acc0 += fmaxf(bf2f((unsigned short)(hv & 0xffffu)) + fmaf(a, we0, be0), 0.f);
    acc1 += fmaxf(bf2f((unsigned short)(hv >> 16)) + fmaf(a, we1, be1), 0.f);
  }
  // degree > 64 tail (essentially never with Poisson(6); correctness fallback)
  for (int j = b + 64; j < e; j++) {
    int s = csr_src[j];
    float a = csr_attr[j];
    unsigned hv = *(const unsigned*)(hb + (size_t)s * DD + d0);
    acc0 += fmaxf(bf2f((unsigned short)(hv & 0xffffu)) + fmaf(a, we0, be0), 0.f);
    acc1 += fmaxf(bf2f((unsigned short)(hv >> 16)) + fmaf(a, we1, be1), 0.f);
  }
  float ep = 1.f + epsp[0];
  float2 hn = *(const float2*)(h + (size_t)n * DD + d0);
  float zx = fmaf(ep, hn.x, acc0);
  float zy = fmaf(ep, hn.y, acc1);
  unsigned pk = (unsigned)f2bf(zx) | ((unsigned)f2bf(zy) << 16);
  *(unsigned*)(zb + (size_t)n * DD + d0) = pk;
}

// ---------------- persistent double-buffered MFMA bf16 GEMM ----------------
// MODE 0: Y = Xb(bf16)@W + b, fused column stats (sum,sumsq) -> stats[256]
// MODE 1: Y = relu( relu(Xin*scale+shift)@W + b );      hbout = bf16(Y) if non-null
// MODE 2: Y = hprev + relu( relu(Xin*scale+shift)@W + b ); same mirror (hprev==Y safe)
// Grid = GB persistent blocks; each grid-strides over 64-row tiles with:
//   W staged once; X double-buffered in LDS; next-next tile prefetched into regs.
template <int MODE>
__global__ __launch_bounds__(256, 2) void k_gemm(
    const unsigned short* __restrict__ Xb, const float* __restrict__ Xin,
    const unsigned short* __restrict__ WT,
    const float* __restrict__ bias, const float* __restrict__ bnp,
    const float* __restrict__ hprev, float* __restrict__ Yout,
    float* __restrict__ stats, unsigned short* __restrict__ hbout) {
  __shared__ unsigned short Wl[128 * 136];     // 34816 B
  __shared__ unsigned short Xl[2][64 * 136];   // 2 x 17408 B  (total 69632 -> 2 blk/CU)
  const int tid = threadIdx.x;
  const int G = gridDim.x;
  const int NT = (NN + 63) >> 6;  // 1563

  // stage W^T bf16 [n][k] -> LDS, once per block
  for (int i = tid; i < 2048; i += 256) {
    int r = i >> 4, c = i & 15;
    *(uint4*)&Wl[r * 136 + c * 8] = *(const uint4*)&WT[r * 128 + c * 8];
  }

  const int lane = tid & 63;
  const int w = tid >> 6;
  const int m = lane & 15;
  const int quad = lane >> 4;

  float bv[8];
#pragma unroll
  for (int ct = 0; ct < 8; ct++) bv[ct] = bias[ct * 16 + m];

  // staging thread mappings
  const int c8 = tid & 15, rr16 = tid >> 4;   // MODE 0: 16B bf16 chunks, rows rr16+it*16
  const int c4 = tid & 31, rr8 = tid >> 5;    // MODE>=1: float4 chunks, rows rr8+it*8
  float4 sc, sf;
  if (MODE >= 1) {
    sc = *(const float4*)(bnp + c4 * 4);
    sf = *(const float4*)(bnp + 128 + c4 * 4);
  }

  uint4 xu[4];   // MODE 0 prefetch regs
  float4 xf[8];  // MODE>=1 prefetch regs

  auto LOADR = [&](int t) {
    int r0 = t << 6;
    if (MODE == 0) {
#pragma unroll
      for (int it = 0; it < 4; it++) {
        int gr = r0 + rr16 + it * 16;
        xu[it] = (gr < NN) ? *(const uint4*)(Xb + (size_t)gr * DD + c8 * 8)
                           : make_uint4(0u, 0u, 0u, 0u);
      }
    } else {
#pragma unroll
      for (int it = 0; it < 8; it++) {
        int gr = r0 + rr8 + it * 8;
        xf[it] = (gr < NN) ? *(const float4*)(Xin + (size_t)gr * DD + c4 * 4)
                           : make_float4(0.f, 0.f, 0.f, 0.f);
      }
    }
  };
  auto STORE_LDS = [&](int b) {
    if (MODE == 0) {
#pragma unroll
      for (int it = 0; it < 4; it++) {
        int row = rr16 + it * 16;
        *(uint4*)&Xl[b][row * 136 + c8 * 8] = xu[it];
      }
    } else {
#pragma unroll
      for (int it = 0; it < 8; it++) {
        int row = rr8 + it * 8;
        float4 v = xf[it];
        v.x = fmaxf(fmaf(v.x, sc.x, sf.x), 0.f);
        v.y = fmaxf(fmaf(v.y, sc.y, sf.y), 0.f);
        v.z = fmaxf(fmaf(v.z, sc.z, sf.z), 0.f);
        v.w = fmaxf(fmaf(v.w, sc.w, sf.w), 0.f);
        ushort4 o;
        o.x = f2bf(v.x); o.y = f2bf(v.y); o.z = f2bf(v.z); o.w = f2bf(v.w);
        *(ushort4*)&Xl[b][row * 136 + c4 * 4] = o;
      }
    }
  };

  float ssum[8], ssq[8];
  if (MODE == 0) {
#pragma unroll
    for (int ct = 0; ct < 8; ct++) { ssum[ct] = 0.f; ssq[ct] = 0.f; }
  }

  const int t0 = blockIdx.x;
  LOADR(t0);
  STORE_LDS(0);
  if (t0 + G < NT) LOADR(t0 + G);
  __syncthreads();  // Xl[0] + Wl ready

  int buf = 0;
  for (int t = t0; t < NT; t += G) {
    const int nxt = t + G;
    if (nxt < NT) {
      STORE_LDS(buf ^ 1);                 // regs hold tile nxt (loaded last iter)
      if (nxt + G < NT) LOADR(nxt + G);   // prefetch tile nxt+G; hides under MFMA+stores
    }

    float4v acc[8];
#pragma unroll
    for (int ct = 0; ct < 8; ct++) acc[ct] = (float4v){bv[ct], bv[ct], bv[ct], bv[ct]};

    const unsigned short* Ap = &Xl[buf][(w * 16 + m) * 136 + quad * 8];
    const unsigned short* Bp = &Wl[m * 136 + quad * 8];
#pragma unroll
    for (int q = 0; q < 4; q++) {
      short8 a = *(const short8*)(Ap + q * 32);
#pragma unroll
      for (int ct = 0; ct < 8; ct++) {
        short8 b = *(const short8*)(Bp + ct * 16 * 136 + q * 32);
        acc[ct] = __builtin_amdgcn_mfma_f32_16x16x32_bf16(a, b, acc[ct], 0, 0, 0);
      }
    }

    const int baserow = (t << 6) + w * 16 + quad * 4;
#pragma unroll
    for (int ct = 0; ct < 8; ct++) {
      int col = ct * 16 + m;
#pragma unroll
      for (int reg = 0; reg < 4; reg++) {
        int r = baserow + reg;
        if (r < NN) {
          float v = acc[ct][reg];
          if (MODE == 0) {
            ssum[ct] += v;
            ssq[ct] = fmaf(v, v, ssq[ct]);
          }
          if (MODE >= 1) v = fmaxf(v, 0.f);
          if (MODE == 2) v += hprev[(size_t)r * DD + col];
          Yout[(size_t)r * DD + col] = v;
          if (MODE >= 1 && hbout) hbout[(size_t)r * DD + col] = f2bf(v);
        }
      }
    }
    __syncthreads();  // all waves done with Xl[buf]; Xl[buf^1] writes visible
    buf ^= 1;
  }

  if (MODE == 0) {
    // block-level stats reduce: regs -> shfl over quads -> LDS over waves -> 1 atomic/thread
    float* sarr = (float*)Xl;   // [4][128]
    float* sqarr = sarr + 512;  // [4][128]
#pragma unroll
    for (int ct = 0; ct < 8; ct++) {
      float s = ssum[ct], s2 = ssq[ct];
      s += __shfl_xor(s, 16); s += __shfl_xor(s, 32);
      s2 += __shfl_xor(s2, 16); s2 += __shfl_xor(s2, 32);
      if (quad == 0) {
        sarr[w * 128 + ct * 16 + m] = s;
        sqarr[w * 128 + ct * 16 + m] = s2;
      }
    }
    __syncthreads();
    if (tid < 128) {
      atomicAdd(&stats[tid], sarr[tid] + sarr[128 + tid] + sarr[256 + tid] + sarr[384 + tid]);
    } else {
      int c = tid - 128;
      atomicAdd(&stats[128 + c], sqarr[c] + sqarr[128 + c] + sqarr[256 + c] + sqarr[384 + c]);
    }
  }
}

__global__ void k_bn_final(const float* __restrict__ stats, const float* __restrict__ gamma,
                           const float* __restrict__ beta, float* __restrict__ bnp) {
  int c = threadIdx.x;
  if (c >= 128) return;
  const float invN = 1.f / (float)NN;
  float mu = stats[c] * invN;
  float var = stats[128 + c] * invN - mu * mu;
  var = fmaxf(var, 0.f);
  float xx = var + 1e-5f;
  float r = rsqrtf(xx);
  r = r * (1.5f - 0.5f * xx * r * r);  // Newton step
  float scale = gamma[c] * r;
  bnp[c] = scale;
  bnp[128 + c] = beta[c] - mu * scale;
}

// ---------------- driver ----------------
static inline size_t align256(size_t x) { return (x + 255) & ~(size_t)255; }

extern "C" void kernel_launch(void* const* d_in, const int* in_sizes, int n_in,
                              void* d_out, int out_size, void* d_ws, size_t ws_size,
                              hipStream_t stream) {
  const float* x     = (const float*)d_in[0];
  const int*   ei    = (const int*)d_in[1];
  const float* attr  = (const float*)d_in[2];
  const float* We    = (const float*)d_in[3];
  const float* be    = (const float*)d_in[4];
  const float* eps   = (const float*)d_in[5];
  const float* W1    = (const float*)d_in[6];
  const float* b1    = (const float*)d_in[7];
  const float* gamma = (const float*)d_in[8];
  const float* beta  = (const float*)d_in[9];
  const float* W2    = (const float*)d_in[10];
  const float* b2    = (const float*)d_in[11];
  float* out = (float*)d_out;

  char* w = (char*)d_ws;
  float* z        = (float*)w; w += align256((size_t)NN * DD * 4);
  unsigned short* hb = (unsigned short*)w; w += align256((size_t)NN * DD * 2);
  unsigned short* zb = (unsigned short*)w; w += align256((size_t)NN * DD * 2);
  int*   row_ptr  = (int*)w;   w += align256((size_t)(NN + 1) * 4);
  int*   counts   = (int*)w;   w += align256((size_t)NN * 4);
  int*   off      = (int*)w;   w += align256((size_t)NN * 4);
  int*   csr_src  = (int*)w;   w += align256((size_t)NE * 4);
  float* csr_attr = (float*)w; w += align256((size_t)NE * 4);
  float* stats    = (float*)w; w += align256(256 * 4);
  float* bnp      = (float*)w; w += align256(256 * 4);
  int*   bsums    = (int*)w;   w += align256(ST * 4);
  int*   boffs    = (int*)w;   w += align256(ST * 4);
  unsigned short* WTb = (unsigned short*)w; w += align256((size_t)8 * 16384 * 2);

  // weight prep + layer-0 bf16 mirror + CSR build
  k_prep<<<512, 256, 0, stream>>>(W1, W2, WTb);
  k_h2b<<<(NN * DD / 4 + 255) / 256, 256, 0, stream>>>(x, hb);
  k_zero_i<<<(NN + 255) / 256, 256, 0, stream>>>(counts, NN);
  k_count<<<(NE + 255) / 256, 256, 0, stream>>>(ei, counts);
  k_scan_part<<<SB, ST, 0, stream>>>(counts, row_ptr, bsums);
  k_scan_bsum<<<1, ST, 0, stream>>>(bsums, boffs, row_ptr);
  k_scan_add<<<SB, ST, 0, stream>>>(boffs, row_ptr, off);
  k_fill<<<(NE + 255) / 256, 256, 0, stream>>>(ei, attr, row_ptr, off, csr_src, csr_attr);

  for (int l = 0; l < NL; l++) {
    const float* h = (l == 0) ? x : out;
    k_agg<<<(NN * 64 + 255) / 256, 256, 0, stream>>>(
        h, hb, row_ptr, csr_src, csr_attr, We + l * DD, be + l * DD, eps + l, zb);
    k_zero_f<<<1, 256, 0, stream>>>(stats, 256);
    // z = zb @ W1 + b1, fused stats
    k_gemm<0><<<GB, 256, 0, stream>>>(zb, nullptr, WTb + (size_t)l * 16384, b1 + l * DD,
                                      nullptr, nullptr, z, stats, nullptr);
    k_bn_final<<<1, 128, 0, stream>>>(stats, gamma + l * DD, beta + l * DD, bnp);
    unsigned short* hbo = (l < NL - 1) ? hb : nullptr;
    if (l == 0)
      k_gemm<1><<<GB, 256, 0, stream>>>(nullptr, z, WTb + (size_t)(4 + l) * 16384, b2 + l * DD,
                                        bnp, nullptr, out, nullptr, hbo);
    else
      k_gemm<2><<<GB, 256, 0, stream>>>(nullptr, z, WTb + (size_t)(4 + l) * 16384, b2 + l * DD,
                                        bnp, out, out, nullptr, hbo);
  }
}

// Round 2
// 598.203 us; speedup vs baseline: 1.3052x; 1.0886x over previous
//
#include <hip/hip_runtime.h>

#define NN 100000
#define NE 600000
#define DD 128
#define NL 4
#define GB 512  // persistent GEMM grid: 2 blocks/CU x 256 CU

typedef __attribute__((ext_vector_type(8))) short short8;
typedef __attribute__((ext_vector_type(4))) float float4v;

__device__ inline unsigned short f2bf(float f) {
  union { float f; unsigned u; } v; v.f = f;
  unsigned r = v.u + 0x7fff + ((v.u >> 16) & 1);  // round-to-nearest-even
  return (unsigned short)(r >> 16);
}
__device__ inline float bf2f(unsigned short u) {
  union { unsigned u; float f; } v; v.u = ((unsigned)u) << 16;
  return v.f;
}

// ---------------- utility ----------------
__global__ void k_zero_i(int* p, int n) {
  int i = blockIdx.x * 256 + threadIdx.x;
  if (i < n) p[i] = 0;
}
__global__ void k_zero_f(float* p, int n) {
  int i = blockIdx.x * 256 + threadIdx.x;
  if (i < n) p[i] = 0.f;
}
// fp32 [NN,128] -> bf16 mirror (layer-0 gather payload only; later layers fused in gemm2)
__global__ void k_h2b(const float* __restrict__ src, unsigned short* __restrict__ dst) {
  int i = blockIdx.x * 256 + threadIdx.x;
  if (i >= NN * DD / 4) return;
  float4 v = ((const float4*)src)[i];
  ushort4 o;
  o.x = f2bf(v.x); o.y = f2bf(v.y); o.z = f2bf(v.z); o.w = f2bf(v.w);
  ((ushort4*)dst)[i] = o;
}

// ---------------- one-time: W1/W2 -> bf16, transposed [n][k] ----------------
__global__ void k_prep(const float* __restrict__ W1, const float* __restrict__ W2,
                       unsigned short* __restrict__ WT) {
  int i = blockIdx.x * 256 + threadIdx.x;  // over 8*16384
  if (i >= 8 * 16384) return;
  int m = i >> 14;
  int el = i & 16383;
  int k = el >> 7;
  int n = el & 127;
  const float* src = (m < 4) ? (W1 + (size_t)m * 16384) : (W2 + (size_t)(m - 4) * 16384);
  WT[(size_t)m * 16384 + n * 128 + k] = f2bf(src[k * 128 + n]);
}

// ---------------- CSR build (once per call) ----------------
__global__ void k_count(const int* __restrict__ ei, int* __restrict__ counts) {
  int e = blockIdx.x * 256 + threadIdx.x;
  if (e < NE) atomicAdd(&counts[ei[NE + e]], 1);
}

#define ST 256
#define SC 2
#define SB ((NN + ST * SC - 1) / (ST * SC))  // 196 blocks

__global__ void k_scan_part(const int* __restrict__ counts, int* __restrict__ row_ptr,
                            int* __restrict__ bsums) {
  __shared__ int s[ST];
  int b = blockIdx.x, t = threadIdx.x;
  int base = b * (ST * SC) + t * SC;
  int v0 = (base < NN) ? counts[base] : 0;
  int v1 = (base + 1 < NN) ? counts[base + 1] : 0;
  int tsum = v0 + v1;
  s[t] = tsum;
  __syncthreads();
  for (int d = 1; d < ST; d <<= 1) {
    int x = (t >= d) ? s[t - d] : 0;
    __syncthreads();
    s[t] += x;
    __syncthreads();
  }
  int excl = s[t] - tsum;
  if (base < NN) row_ptr[base] = excl;
  if (base + 1 < NN) row_ptr[base + 1] = excl + v0;
  if (t == ST - 1) bsums[b] = s[t];
}

__global__ void k_scan_bsum(const int* __restrict__ bsums, int* __restrict__ boffs,
                            int* __restrict__ row_ptr) {
  __shared__ int s[ST];
  int t = threadIdx.x;
  int v = (t < SB) ? bsums[t] : 0;
  s[t] = v;
  __syncthreads();
  for (int d = 1; d < ST; d <<= 1) {
    int x = (t >= d) ? s[t - d] : 0;
    __syncthreads();
    s[t] += x;
    __syncthreads();
  }
  if (t < SB) boffs[t] = s[t] - v;
  if (t == ST - 1) row_ptr[NN] = s[t];
}

__global__ void k_scan_add(const int* __restrict__ boffs, int* __restrict__ row_ptr,
                           int* __restrict__ off) {
  int b = blockIdx.x, t = threadIdx.x;
  int base = b * (ST * SC) + t * SC;
  int o = boffs[b];
  if (base < NN) { row_ptr[base] += o; off[base] = 0; }
  if (base + 1 < NN) { row_ptr[base + 1] += o; off[base + 1] = 0; }
}

__global__ void k_fill(const int* __restrict__ ei, const float* __restrict__ attr,
                       const int* __restrict__ row_ptr, int* __restrict__ off,
                       int* __restrict__ csr_src, float* __restrict__ csr_attr) {
  int e = blockIdx.x * 256 + threadIdx.x;
  if (e >= NE) return;
  int srcv = ei[e];
  int dstv = ei[NE + e];
  int pos = atomicAdd(&off[dstv], 1);
  int idx = row_ptr[dstv] + pos;
  csr_src[idx] = srcv;
  csr_attr[idx] = attr[e];
}

// ------- aggregation: zb = bf16( (1+eps)*h + sum relu(hb[src]+attr*We+be) ) -------
__global__ void k_agg(const float* __restrict__ h, const unsigned short* __restrict__ hb,
                      const int* __restrict__ row_ptr,
                      const int* __restrict__ csr_src, const float* __restrict__ csr_attr,
                      const float* __restrict__ We, const float* __restrict__ be,
                      const float* __restrict__ epsp, unsigned short* __restrict__ zb) {
  int gid = blockIdx.x * blockDim.x + threadIdx.x;
  int n = gid >> 6;
  int lane = gid & 63;
  if (n >= NN) return;
  int d0 = lane * 2;
  float we0 = We[d0], we1 = We[d0 + 1];
  float be0 = be[d0], be1 = be[d0 + 1];
  int b = row_ptr[n], e = row_ptr[n + 1];
  int deg = e - b;
  int cnt = (deg < 64) ? deg : 64;
  int myidx = (lane < cnt) ? csr_src[b + lane] : 0;
  float myatt = (lane < cnt) ? csr_attr[b + lane] : 0.f;
  float acc0 = 0.f, acc1 = 0.f;
  int i = 0;
  for (; i + 4 <= cnt; i += 4) {
    int s0 = __shfl(myidx, i);
    int s1 = __shfl(myidx, i + 1);
    int s2 = __shfl(myidx, i + 2);
    int s3 = __shfl(myidx, i + 3);
    float a0 = __shfl(myatt, i);
    float a1 = __shfl(myatt, i + 1);
    float a2 = __shfl(myatt, i + 2);
    float a3 = __shfl(myatt, i + 3);
    unsigned hv0 = *(const unsigned*)(hb + (size_t)s0 * DD + d0);
    unsigned hv1 = *(const unsigned*)(hb + (size_t)s1 * DD + d0);
    unsigned hv2 = *(const unsigned*)(hb + (size_t)s2 * DD + d0);
    unsigned hv3 = *(const unsigned*)(hb + (size_t)s3 * DD + d0);
    acc0 += fmaxf(bf2f((unsigned short)(hv0 & 0xffffu)) + fmaf(a0, we0, be0), 0.f);
    acc1 += fmaxf(bf2f((unsigned short)(hv0 >> 16)) + fmaf(a0, we1, be1), 0.f);
    acc0 += fmaxf(bf2f((unsigned short)(hv1 & 0xffffu)) + fmaf(a1, we0, be0), 0.f);
    acc1 += fmaxf(bf2f((unsigned short)(hv1 >> 16)) + fmaf(a1, we1, be1), 0.f);
    acc0 += fmaxf(bf2f((unsigned short)(hv2 & 0xffffu)) + fmaf(a2, we0, be0), 0.f);
    acc1 += fmaxf(bf2f((unsigned short)(hv2 >> 16)) + fmaf(a2, we1, be1), 0.f);
    acc0 += fmaxf(bf2f((unsigned short)(hv3 & 0xffffu)) + fmaf(a3, we0, be0), 0.f);
    acc1 += fmaxf(bf2f((unsigned short)(hv3 >> 16)) + fmaf(a3, we1, be1), 0.f);
  }
  for (; i < cnt; i++) {
    int s = __shfl(myidx, i);
    float a = __shfl(myatt, i);
    unsigned hv = *(const unsigned*)(hb + (size_t)s * DD + d0);
    acc0 += fmaxf(bf2f((unsigned short)(hv & 0xffffu)) + fmaf(a, we0, be0), 0.f);
    acc1 += fmaxf(bf2f((unsigned short)(hv >> 16)) + fmaf(a, we1, be1), 0.f);
  }
  for (int j = b + 64; j < e; j++) {
    int s = csr_src[j];
    float a = csr_attr[j];
    unsigned hv = *(const unsigned*)(hb + (size_t)s * DD + d0);
    acc0 += fmaxf(bf2f((unsigned short)(hv & 0xffffu)) + fmaf(a, we0, be0), 0.f);
    acc1 += fmaxf(bf2f((unsigned short)(hv >> 16)) + fmaf(a, we1, be1), 0.f);
  }
  float ep = 1.f + epsp[0];
  float2 hn = *(const float2*)(h + (size_t)n * DD + d0);
  float zx = fmaf(ep, hn.x, acc0);
  float zy = fmaf(ep, hn.y, acc1);
  unsigned pk = (unsigned)f2bf(zx) | ((unsigned)f2bf(zy) << 16);
  *(unsigned*)(zb + (size_t)n * DD + d0) = pk;
}

// ---------------- persistent double-buffered MFMA bf16 GEMM ----------------
// Operand-swapped (A = W^T tile, B = X rows): each lane owns ONE output row and
// 4 consecutive cols per ct chunk -> float4/dwordx4 epilogue.
// MODE 0: z2(bf16) = Xb@W + b, fused column stats (sum,sumsq) -> stats[256]
// MODE 1: Y = relu( relu(bn(Xb))@W + b );       Ybf = bf16(Y) if non-null
// MODE 2: Y = hprev + relu( relu(bn(Xb))@W + b ); same mirror (hprev==Y safe)
// All modes read bf16 X. Per-tile sync is lgkmcnt(0)+s_barrier only: epilogue
// global stores are never drained inside the loop (T4 counted-wait discipline).
template <int MODE>
__global__ __launch_bounds__(256, 2) void k_gemm(
    const unsigned short* __restrict__ Xb, const unsigned short* __restrict__ WT,
    const float* __restrict__ bias, const float* __restrict__ bnp,
    const float* __restrict__ hprev, float* __restrict__ Yout,
    unsigned short* __restrict__ Ybf, float* __restrict__ stats) {
  __shared__ unsigned short Wl[128 * 136];     // 34816 B
  __shared__ unsigned short Xl[2][64 * 136];   // 2 x 17408 B  (total 69632 -> 2 blk/CU)
  const int tid = threadIdx.x;
  const int G = gridDim.x;
  const int NT = (NN + 63) >> 6;  // 1563

  // stage W^T bf16 [n][k] -> LDS, once per block
  for (int i = tid; i < 2048; i += 256) {
    int rr = i >> 4, c = i & 15;
    *(uint4*)&Wl[rr * 136 + c * 8] = *(const uint4*)&WT[rr * 128 + c * 8];
  }

  const int lane = tid & 63;
  const int w = tid >> 6;
  const int m = lane & 15;
  const int quad = lane >> 4;

  // staging mapping: 16B bf16 chunks; c8 = chunk, rows rr16 + it*16
  const int c8 = tid & 15, rr16 = tid >> 4;
  float scl[8], sfl[8];
  if (MODE >= 1) {
#pragma unroll
    for (int j = 0; j < 8; j++) {
      scl[j] = bnp[c8 * 8 + j];
      sfl[j] = bnp[128 + c8 * 8 + j];
    }
  }

  uint4 xu[4];  // prefetch regs (8 bf16 each)
  auto LOADR = [&](int t) {
    int r0 = t << 6;
#pragma unroll
    for (int it = 0; it < 4; it++) {
      int gr = r0 + rr16 + it * 16;
      xu[it] = (gr < NN) ? *(const uint4*)(Xb + (size_t)gr * DD + c8 * 8)
                         : make_uint4(0u, 0u, 0u, 0u);
    }
  };
  auto STORE_LDS = [&](int b) {
#pragma unroll
    for (int it = 0; it < 4; it++) {
      int row = rr16 + it * 16;
      uint4 u = xu[it];
      if (MODE >= 1) {
        unsigned p[4] = {u.x, u.y, u.z, u.w};
#pragma unroll
        for (int j = 0; j < 4; j++) {
          float lo = bf2f((unsigned short)(p[j] & 0xffffu));
          float hi = bf2f((unsigned short)(p[j] >> 16));
          lo = fmaxf(fmaf(lo, scl[2 * j], sfl[2 * j]), 0.f);
          hi = fmaxf(fmaf(hi, scl[2 * j + 1], sfl[2 * j + 1]), 0.f);
          p[j] = (unsigned)f2bf(lo) | ((unsigned)f2bf(hi) << 16);
        }
        u = make_uint4(p[0], p[1], p[2], p[3]);
      }
      *(uint4*)&Xl[b][row * 136 + c8 * 8] = u;
    }
  };

  float4v ssum[8], ssq[8];
  if (MODE == 0) {
#pragma unroll
    for (int ct = 0; ct < 8; ct++) {
      ssum[ct] = (float4v){0.f, 0.f, 0.f, 0.f};
      ssq[ct] = (float4v){0.f, 0.f, 0.f, 0.f};
    }
  }

  const int t0 = blockIdx.x;
  LOADR(t0);
  STORE_LDS(0);
  if (t0 + G < NT) LOADR(t0 + G);
  __syncthreads();  // Xl[0] + Wl ready

  int buf = 0;
  for (int t = t0; t < NT; t += G) {
    const int nxt = t + G;
    if (nxt < NT) {
      STORE_LDS(buf ^ 1);                 // regs hold tile nxt (loaded last iter)
      if (nxt + G < NT) LOADR(nxt + G);   // prefetch tile nxt+G
    }

    float4v acc[8];
#pragma unroll
    for (int ct = 0; ct < 8; ct++) {
      float4 b4 = *(const float4*)&bias[ct * 16 + quad * 4];
      acc[ct] = (float4v){b4.x, b4.y, b4.z, b4.w};
    }

    // A = W^T rows (output cols), B = X rows (output rows in lanes)
    const unsigned short* Ap = &Wl[m * 136 + quad * 8];
    const unsigned short* Bp = &Xl[buf][(w * 16 + m) * 136 + quad * 8];
#pragma unroll
    for (int q = 0; q < 4; q++) {
      short8 bfrag = *(const short8*)(Bp + q * 32);
#pragma unroll
      for (int ct = 0; ct < 8; ct++) {
        short8 afrag = *(const short8*)(Ap + ct * 16 * 136 + q * 32);
        acc[ct] = __builtin_amdgcn_mfma_f32_16x16x32_bf16(afrag, bfrag, acc[ct], 0, 0, 0);
      }
    }

    // LDS-only fence: our ds_reads (and this iter's ds_writes) drained, then
    // block barrier. Global stores below stay in flight across tiles.
    asm volatile("s_waitcnt lgkmcnt(0)" ::: "memory");
    __builtin_amdgcn_s_barrier();

    const int r = (t << 6) + w * 16 + m;  // this lane's output row
    if (r < NN) {
      const size_t rb = (size_t)r * DD;
#pragma unroll
      for (int ct = 0; ct < 8; ct++) {
        float4v v = acc[ct];
        const int col = ct * 16 + quad * 4;
        if (MODE == 0) {
          ssum[ct] += v;
          ssq[ct] += v * v;
          ushort4 o;
          o.x = f2bf(v[0]); o.y = f2bf(v[1]); o.z = f2bf(v[2]); o.w = f2bf(v[3]);
          *(ushort4*)&Ybf[rb + col] = o;
        } else {
          v[0] = fmaxf(v[0], 0.f); v[1] = fmaxf(v[1], 0.f);
          v[2] = fmaxf(v[2], 0.f); v[3] = fmaxf(v[3], 0.f);
          if (MODE == 2) {
            float4 hp = *(const float4*)&hprev[rb + col];
            v[0] += hp.x; v[1] += hp.y; v[2] += hp.z; v[3] += hp.w;
          }
          *(float4v*)&Yout[rb + col] = v;
          if (Ybf) {
            ushort4 o;
            o.x = f2bf(v[0]); o.y = f2bf(v[1]); o.z = f2bf(v[2]); o.w = f2bf(v[3]);
            *(ushort4*)&Ybf[rb + col] = o;
          }
        }
      }
    }
    buf ^= 1;
  }

  if (MODE == 0) {
    // per-lane col sums (cols fixed per lane across all tiles):
    // reduce over the 16 lanes (m) of each quad, then over waves via LDS.
    float* sarr = (float*)Xl;   // [4][128]
    float* sqarr = sarr + 512;  // [4][128]
#pragma unroll
    for (int ct = 0; ct < 8; ct++) {
      float4v s = ssum[ct], s2 = ssq[ct];
#pragma unroll
      for (int d = 1; d < 16; d <<= 1) {
#pragma unroll
        for (int j = 0; j < 4; j++) {
          s[j] += __shfl_xor(s[j], d);
          s2[j] += __shfl_xor(s2[j], d);
        }
      }
      if (m == 0) {
        *(float4v*)&sarr[w * 128 + ct * 16 + quad * 4] = s;
        *(float4v*)&sqarr[w * 128 + ct * 16 + quad * 4] = s2;
      }
    }
    __syncthreads();
    if (tid < 128) {
      atomicAdd(&stats[tid], sarr[tid] + sarr[128 + tid] + sarr[256 + tid] + sarr[384 + tid]);
    } else {
      int c = tid - 128;
      atomicAdd(&stats[128 + c], sqarr[c] + sqarr[128 + c] + sqarr[256 + c] + sqarr[384 + c]);
    }
  }
}

__global__ void k_bn_final(const float* __restrict__ stats, const float* __restrict__ gamma,
                           const float* __restrict__ beta, float* __restrict__ bnp) {
  int c = threadIdx.x;
  if (c >= 128) return;
  const float invN = 1.f / (float)NN;
  float mu = stats[c] * invN;
  float var = stats[128 + c] * invN - mu * mu;
  var = fmaxf(var, 0.f);
  float xx = var + 1e-5f;
  float r = rsqrtf(xx);
  r = r * (1.5f - 0.5f * xx * r * r);  // Newton step
  float scale = gamma[c] * r;
  bnp[c] = scale;
  bnp[128 + c] = beta[c] - mu * scale;
}

// ---------------- driver ----------------
static inline size_t align256(size_t x) { return (x + 255) & ~(size_t)255; }

extern "C" void kernel_launch(void* const* d_in, const int* in_sizes, int n_in,
                              void* d_out, int out_size, void* d_ws, size_t ws_size,
                              hipStream_t stream) {
  const float* x     = (const float*)d_in[0];
  const int*   ei    = (const int*)d_in[1];
  const float* attr  = (const float*)d_in[2];
  const float* We    = (const float*)d_in[3];
  const float* be    = (const float*)d_in[4];
  const float* eps   = (const float*)d_in[5];
  const float* W1    = (const float*)d_in[6];
  const float* b1    = (const float*)d_in[7];
  const float* gamma = (const float*)d_in[8];
  const float* beta  = (const float*)d_in[9];
  const float* W2    = (const float*)d_in[10];
  const float* b2    = (const float*)d_in[11];
  float* out = (float*)d_out;

  char* w = (char*)d_ws;
  unsigned short* z2 = (unsigned short*)w; w += align256((size_t)NN * DD * 2);
  unsigned short* hb = (unsigned short*)w; w += align256((size_t)NN * DD * 2);
  unsigned short* zb = (unsigned short*)w; w += align256((size_t)NN * DD * 2);
  int*   row_ptr  = (int*)w;   w += align256((size_t)(NN + 1) * 4);
  int*   counts   = (int*)w;   w += align256((size_t)NN * 4);
  int*   off      = (int*)w;   w += align256((size_t)NN * 4);
  int*   csr_src  = (int*)w;   w += align256((size_t)NE * 4);
  float* csr_attr = (float*)w; w += align256((size_t)NE * 4);
  float* stats    = (float*)w; w += align256(256 * 4);
  float* bnp      = (float*)w; w += align256(256 * 4);
  int*   bsums    = (int*)w;   w += align256(ST * 4);
  int*   boffs    = (int*)w;   w += align256(ST * 4);
  unsigned short* WTb = (unsigned short*)w; w += align256((size_t)8 * 16384 * 2);

  // weight prep + layer-0 bf16 mirror + CSR build
  k_prep<<<512, 256, 0, stream>>>(W1, W2, WTb);
  k_h2b<<<(NN * DD / 4 + 255) / 256, 256, 0, stream>>>(x, hb);
  k_zero_i<<<(NN + 255) / 256, 256, 0, stream>>>(counts, NN);
  k_count<<<(NE + 255) / 256, 256, 0, stream>>>(ei, counts);
  k_scan_part<<<SB, ST, 0, stream>>>(counts, row_ptr, bsums);
  k_scan_bsum<<<1, ST, 0, stream>>>(bsums, boffs, row_ptr);
  k_scan_add<<<SB, ST, 0, stream>>>(boffs, row_ptr, off);
  k_fill<<<(NE + 255) / 256, 256, 0, stream>>>(ei, attr, row_ptr, off, csr_src, csr_attr);

  for (int l = 0; l < NL; l++) {
    const float* h = (l == 0) ? x : out;
    k_agg<<<(NN * 64 + 255) / 256, 256, 0, stream>>>(
        h, hb, row_ptr, csr_src, csr_attr, We + l * DD, be + l * DD, eps + l, zb);
    k_zero_f<<<1, 256, 0, stream>>>(stats, 256);
    // z2(bf16) = zb @ W1 + b1, fused stats
    k_gemm<0><<<GB, 256, 0, stream>>>(zb, WTb + (size_t)l * 16384, b1 + l * DD,
                                      nullptr, nullptr, nullptr, z2, stats);
    k_bn_final<<<1, 128, 0, stream>>>(stats, gamma + l * DD, beta + l * DD, bnp);
    unsigned short* hbo = (l < NL - 1) ? hb : nullptr;
    if (l == 0)
      k_gemm<1><<<GB, 256, 0, stream>>>(z2, WTb + (size_t)(4 + l) * 16384, b2 + l * DD,
                                        bnp, nullptr, out, hbo, nullptr);
    else
      k_gemm<2><<<GB, 256, 0, stream>>>(z2, WTb + (size_t)(4 + l) * 16384, b2 + l * DD,
                                        bnp, out, out, hbo, nullptr);
  }
}

// Round 3
// 573.087 us; speedup vs baseline: 1.3624x; 1.0438x over previous
//
#include <hip/hip_runtime.h>

#define NN 100000
#define NE 600000
#define DD 128
#define NL 4
#define GB 512  // persistent GEMM grid: 2 blocks/CU x 256 CU

typedef __attribute__((ext_vector_type(8))) short short8;
typedef __attribute__((ext_vector_type(4))) float float4v;

__device__ inline unsigned short f2bf(float f) {
  union { float f; unsigned u; } v; v.f = f;
  unsigned r = v.u + 0x7fff + ((v.u >> 16) & 1);  // round-to-nearest-even
  return (unsigned short)(r >> 16);
}
__device__ inline float bf2f(unsigned short u) {
  union { unsigned u; float f; } v; v.u = ((unsigned)u) << 16;
  return v.f;
}

// ---------------- setup: fp32 x -> bf16 mirror + zero counts/stats ----------------
__global__ void k_h2b(const float* __restrict__ src, unsigned short* __restrict__ dst,
                      float* __restrict__ stats4, int* __restrict__ counts) {
  int i = blockIdx.x * 256 + threadIdx.x;
  if (i < NL * 256) stats4[i] = 0.f;
  if (i < NN) counts[i] = 0;
  if (i >= NN * DD / 4) return;
  float4 v = ((const float4*)src)[i];
  ushort4 o;
  o.x = f2bf(v.x); o.y = f2bf(v.y); o.z = f2bf(v.z); o.w = f2bf(v.w);
  ((ushort4*)dst)[i] = o;
}

// ---------------- one-time: W1/W2 -> bf16, transposed [n][k] ----------------
__global__ void k_prep(const float* __restrict__ W1, const float* __restrict__ W2,
                       unsigned short* __restrict__ WT) {
  int i = blockIdx.x * 256 + threadIdx.x;  // over 8*16384
  if (i >= 8 * 16384) return;
  int m = i >> 14;
  int el = i & 16383;
  int k = el >> 7;
  int n = el & 127;
  const float* src = (m < 4) ? (W1 + (size_t)m * 16384) : (W2 + (size_t)(m - 4) * 16384);
  WT[(size_t)m * 16384 + n * 128 + k] = f2bf(src[k * 128 + n]);
}

// ---------------- CSR build (once per call) ----------------
__global__ void k_count(const int* __restrict__ ei, int* __restrict__ counts) {
  int e = blockIdx.x * 256 + threadIdx.x;
  if (e < NE) atomicAdd(&counts[ei[NE + e]], 1);
}

#define ST 256
#define SC 2
#define SB ((NN + ST * SC - 1) / (ST * SC))  // 196 blocks

__global__ void k_scan_part(const int* __restrict__ counts, int* __restrict__ row_ptr,
                            int* __restrict__ bsums) {
  __shared__ int s[ST];
  int b = blockIdx.x, t = threadIdx.x;
  int base = b * (ST * SC) + t * SC;
  int v0 = (base < NN) ? counts[base] : 0;
  int v1 = (base + 1 < NN) ? counts[base + 1] : 0;
  int tsum = v0 + v1;
  s[t] = tsum;
  __syncthreads();
  for (int d = 1; d < ST; d <<= 1) {
    int x = (t >= d) ? s[t - d] : 0;
    __syncthreads();
    s[t] += x;
    __syncthreads();
  }
  int excl = s[t] - tsum;
  if (base < NN) row_ptr[base] = excl;
  if (base + 1 < NN) row_ptr[base + 1] = excl + v0;
  if (t == ST - 1) bsums[b] = s[t];
}

__global__ void k_scan_bsum(const int* __restrict__ bsums, int* __restrict__ boffs,
                            int* __restrict__ row_ptr) {
  __shared__ int s[ST];
  int t = threadIdx.x;
  int v = (t < SB) ? bsums[t] : 0;
  s[t] = v;
  __syncthreads();
  for (int d = 1; d < ST; d <<= 1) {
    int x = (t >= d) ? s[t - d] : 0;
    __syncthreads();
    s[t] += x;
    __syncthreads();
  }
  if (t < SB) boffs[t] = s[t] - v;
  if (t == ST - 1) row_ptr[NN] = s[t];
}

__global__ void k_scan_add(const int* __restrict__ boffs, int* __restrict__ row_ptr,
                           int* __restrict__ off) {
  int b = blockIdx.x, t = threadIdx.x;
  int base = b * (ST * SC) + t * SC;
  int o = boffs[b];
  if (base < NN) { row_ptr[base] += o; off[base] = 0; }
  if (base + 1 < NN) { row_ptr[base + 1] += o; off[base + 1] = 0; }
}

// packed CSR record: .x = src node, .y = attr bits (one 8B store per edge)
__global__ void k_fill(const int* __restrict__ ei, const float* __restrict__ attr,
                       const int* __restrict__ row_ptr, int* __restrict__ off,
                       int2* __restrict__ csr) {
  int e = blockIdx.x * 256 + threadIdx.x;
  if (e >= NE) return;
  int srcv = ei[e];
  int dstv = ei[NE + e];
  int pos = atomicAdd(&off[dstv], 1);
  int idx = row_ptr[dstv] + pos;
  csr[idx] = make_int2(srcv, __float_as_int(attr[e]));
}

// ------- aggregation: zb = bf16( (1+eps)*hb[n] + sum relu(hb[src]+attr*We+be) ) -------
// Self-term read from the bf16 mirror (saves the 51.2 MB fp32 h read; the result is
// rounded to bf16 immediately after, so the extra error is <= 1 ulp of zb).
__global__ void k_agg(const unsigned short* __restrict__ hb,
                      const int* __restrict__ row_ptr, const int2* __restrict__ csr,
                      const float* __restrict__ We, const float* __restrict__ be,
                      const float* __restrict__ epsp, unsigned short* __restrict__ zb) {
  int gid = blockIdx.x * blockDim.x + threadIdx.x;
  int n = gid >> 6;
  int lane = gid & 63;
  if (n >= NN) return;
  int d0 = lane * 2;
  float we0 = We[d0], we1 = We[d0 + 1];
  float be0 = be[d0], be1 = be[d0 + 1];
  int b = row_ptr[n], e = row_ptr[n + 1];
  int deg = e - b;
  int cnt = (deg < 64) ? deg : 64;
  int2 rec = (lane < cnt) ? csr[b + lane] : make_int2(0, 0);
  int myidx = rec.x;
  float myatt = __int_as_float(rec.y);
  if (lane >= cnt) myatt = 0.f;
  float acc0 = 0.f, acc1 = 0.f;
  int i = 0;
  for (; i + 4 <= cnt; i += 4) {
    int s0 = __shfl(myidx, i);
    int s1 = __shfl(myidx, i + 1);
    int s2 = __shfl(myidx, i + 2);
    int s3 = __shfl(myidx, i + 3);
    float a0 = __shfl(myatt, i);
    float a1 = __shfl(myatt, i + 1);
    float a2 = __shfl(myatt, i + 2);
    float a3 = __shfl(myatt, i + 3);
    unsigned hv0 = *(const unsigned*)(hb + (size_t)s0 * DD + d0);
    unsigned hv1 = *(const unsigned*)(hb + (size_t)s1 * DD + d0);
    unsigned hv2 = *(const unsigned*)(hb + (size_t)s2 * DD + d0);
    unsigned hv3 = *(const unsigned*)(hb + (size_t)s3 * DD + d0);
    acc0 += fmaxf(bf2f((unsigned short)(hv0 & 0xffffu)) + fmaf(a0, we0, be0), 0.f);
    acc1 += fmaxf(bf2f((unsigned short)(hv0 >> 16)) + fmaf(a0, we1, be1), 0.f);
    acc0 += fmaxf(bf2f((unsigned short)(hv1 & 0xffffu)) + fmaf(a1, we0, be0), 0.f);
    acc1 += fmaxf(bf2f((unsigned short)(hv1 >> 16)) + fmaf(a1, we1, be1), 0.f);
    acc0 += fmaxf(bf2f((unsigned short)(hv2 & 0xffffu)) + fmaf(a2, we0, be0), 0.f);
    acc1 += fmaxf(bf2f((unsigned short)(hv2 >> 16)) + fmaf(a2, we1, be1), 0.f);
    acc0 += fmaxf(bf2f((unsigned short)(hv3 & 0xffffu)) + fmaf(a3, we0, be0), 0.f);
    acc1 += fmaxf(bf2f((unsigned short)(hv3 >> 16)) + fmaf(a3, we1, be1), 0.f);
  }
  for (; i < cnt; i++) {
    int s = __shfl(myidx, i);
    float a = __shfl(myatt, i);
    unsigned hv = *(const unsigned*)(hb + (size_t)s * DD + d0);
    acc0 += fmaxf(bf2f((unsigned short)(hv & 0xffffu)) + fmaf(a, we0, be0), 0.f);
    acc1 += fmaxf(bf2f((unsigned short)(hv >> 16)) + fmaf(a, we1, be1), 0.f);
  }
  // degree > 64 tail (rare; correctness fallback)
  for (int j = b + 64; j < e; j++) {
    int2 r2 = csr[j];
    float a = __int_as_float(r2.y);
    unsigned hv = *(const unsigned*)(hb + (size_t)r2.x * DD + d0);
    acc0 += fmaxf(bf2f((unsigned short)(hv & 0xffffu)) + fmaf(a, we0, be0), 0.f);
    acc1 += fmaxf(bf2f((unsigned short)(hv >> 16)) + fmaf(a, we1, be1), 0.f);
  }
  float ep = 1.f + epsp[0];
  unsigned hs = *(const unsigned*)(hb + (size_t)n * DD + d0);
  float zx = fmaf(ep, bf2f((unsigned short)(hs & 0xffffu)), acc0);
  float zy = fmaf(ep, bf2f((unsigned short)(hs >> 16)), acc1);
  unsigned pk = (unsigned)f2bf(zx) | ((unsigned)f2bf(zy) << 16);
  *(unsigned*)(zb + (size_t)n * DD + d0) = pk;
}

// ---------------- persistent double-buffered MFMA bf16 GEMM ----------------
// Operand-swapped (A = W^T tile, B = X rows): each lane owns ONE output row and
// 4 consecutive cols per ct chunk -> float4/dwordx4 epilogue.
// MODE 0: z2(bf16) = Xb@W + b, fused column stats (sum,sumsq) -> stats[256]
// MODE 1: Y = relu( relu(bn(Xb))@W + b );       Ybf = bf16(Y) if non-null
// MODE 2: Y = hprev + relu( relu(bn(Xb))@W + b ); same mirror (hprev==Y safe)
// MODE 1/2 compute BN scale/shift from stats+gamma+beta in-kernel (per block).
template <int MODE>
__global__ __launch_bounds__(256, 2) void k_gemm(
    const unsigned short* __restrict__ Xb, const unsigned short* __restrict__ WT,
    const float* __restrict__ bias, float* __restrict__ stats,
    const float* __restrict__ gamma, const float* __restrict__ beta,
    const float* __restrict__ hprev, float* __restrict__ Yout,
    unsigned short* __restrict__ Ybf) {
  __shared__ unsigned short Wl[128 * 136];     // 34816 B
  __shared__ unsigned short Xl[2][64 * 136];   // 2 x 17408 B
  __shared__ float bns[256];                   // 1024 B -> total 70656 B, 2 blk/CU
  const int tid = threadIdx.x;
  const int G = gridDim.x;
  const int NT = (NN + 63) >> 6;  // 1563

  // stage W^T bf16 [n][k] -> LDS, once per block
  for (int i = tid; i < 2048; i += 256) {
    int rr = i >> 4, c = i & 15;
    *(uint4*)&Wl[rr * 136 + c * 8] = *(const uint4*)&WT[rr * 128 + c * 8];
  }

  const int lane = tid & 63;
  const int w = tid >> 6;
  const int m = lane & 15;
  const int quad = lane >> 4;

  // staging mapping: 16B bf16 chunks; c8 = chunk, rows rr16 + it*16
  const int c8 = tid & 15, rr16 = tid >> 4;
  float scl[8], sfl[8];
  if (MODE >= 1) {
    if (tid < 128) {
      const float invN = 1.f / (float)NN;
      float mu = stats[tid] * invN;
      float var = fmaxf(stats[128 + tid] * invN - mu * mu, 0.f);
      float xx = var + 1e-5f;
      float r = rsqrtf(xx);
      r = r * (1.5f - 0.5f * xx * r * r);  // Newton step
      float scale = gamma[tid] * r;
      bns[tid] = scale;
      bns[128 + tid] = beta[tid] - mu * scale;
    }
    __syncthreads();
#pragma unroll
    for (int j = 0; j < 8; j++) {
      scl[j] = bns[c8 * 8 + j];
      sfl[j] = bns[128 + c8 * 8 + j];
    }
  }

  uint4 xu[4];  // prefetch regs (8 bf16 each)
  auto LOADR = [&](int t) {
    int r0 = t << 6;
#pragma unroll
    for (int it = 0; it < 4; it++) {
      int gr = r0 + rr16 + it * 16;
      xu[it] = (gr < NN) ? *(const uint4*)(Xb + (size_t)gr * DD + c8 * 8)
                         : make_uint4(0u, 0u, 0u, 0u);
    }
  };
  auto STORE_LDS = [&](int b) {
#pragma unroll
    for (int it = 0; it < 4; it++) {
      int row = rr16 + it * 16;
      uint4 u = xu[it];
      if (MODE >= 1) {
        unsigned p[4] = {u.x, u.y, u.z, u.w};
#pragma unroll
        for (int j = 0; j < 4; j++) {
          float lo = bf2f((unsigned short)(p[j] & 0xffffu));
          float hi = bf2f((unsigned short)(p[j] >> 16));
          lo = fmaxf(fmaf(lo, scl[2 * j], sfl[2 * j]), 0.f);
          hi = fmaxf(fmaf(hi, scl[2 * j + 1], sfl[2 * j + 1]), 0.f);
          p[j] = (unsigned)f2bf(lo) | ((unsigned)f2bf(hi) << 16);
        }
        u = make_uint4(p[0], p[1], p[2], p[3]);
      }
      *(uint4*)&Xl[b][row * 136 + c8 * 8] = u;
    }
  };

  float4v ssum[8], ssq[8];
  if (MODE == 0) {
#pragma unroll
    for (int ct = 0; ct < 8; ct++) {
      ssum[ct] = (float4v){0.f, 0.f, 0.f, 0.f};
      ssq[ct] = (float4v){0.f, 0.f, 0.f, 0.f};
    }
  }

  const int t0 = blockIdx.x;
  LOADR(t0);
  STORE_LDS(0);
  if (t0 + G < NT) LOADR(t0 + G);
  __syncthreads();  // Xl[0] + Wl ready

  int buf = 0;
  for (int t = t0; t < NT; t += G) {
    const int nxt = t + G;
    if (nxt < NT) {
      STORE_LDS(buf ^ 1);                 // regs hold tile nxt (loaded last iter)
      if (nxt + G < NT) LOADR(nxt + G);   // prefetch tile nxt+G
    }

    float4v acc[8];
#pragma unroll
    for (int ct = 0; ct < 8; ct++) {
      float4 b4 = *(const float4*)&bias[ct * 16 + quad * 4];
      acc[ct] = (float4v){b4.x, b4.y, b4.z, b4.w};
    }

    // A = W^T rows (output cols), B = X rows (output rows in lanes)
    const unsigned short* Ap = &Wl[m * 136 + quad * 8];
    const unsigned short* Bp = &Xl[buf][(w * 16 + m) * 136 + quad * 8];
#pragma unroll
    for (int q = 0; q < 4; q++) {
      short8 bfrag = *(const short8*)(Bp + q * 32);
#pragma unroll
      for (int ct = 0; ct < 8; ct++) {
        short8 afrag = *(const short8*)(Ap + ct * 16 * 136 + q * 32);
        acc[ct] = __builtin_amdgcn_mfma_f32_16x16x32_bf16(afrag, bfrag, acc[ct], 0, 0, 0);
      }
    }

    // LDS-only fence; epilogue global stores stay in flight across tiles.
    asm volatile("s_waitcnt lgkmcnt(0)" ::: "memory");
    __builtin_amdgcn_s_barrier();

    const int r = (t << 6) + w * 16 + m;  // this lane's output row
    if (r < NN) {
      const size_t rb = (size_t)r * DD;
#pragma unroll
      for (int ct = 0; ct < 8; ct++) {
        float4v v = acc[ct];
        const int col = ct * 16 + quad * 4;
        if (MODE == 0) {
          ssum[ct] += v;
          ssq[ct] += v * v;
          ushort4 o;
          o.x = f2bf(v[0]); o.y = f2bf(v[1]); o.z = f2bf(v[2]); o.w = f2bf(v[3]);
          *(ushort4*)&Ybf[rb + col] = o;
        } else {
          v[0] = fmaxf(v[0], 0.f); v[1] = fmaxf(v[1], 0.f);
          v[2] = fmaxf(v[2], 0.f); v[3] = fmaxf(v[3], 0.f);
          if (MODE == 2) {
            float4 hp = *(const float4*)&hprev[rb + col];
            v[0] += hp.x; v[1] += hp.y; v[2] += hp.z; v[3] += hp.w;
          }
          *(float4v*)&Yout[rb + col] = v;
          if (Ybf) {
            ushort4 o;
            o.x = f2bf(v[0]); o.y = f2bf(v[1]); o.z = f2bf(v[2]); o.w = f2bf(v[3]);
            *(ushort4*)&Ybf[rb + col] = o;
          }
        }
      }
    }
    buf ^= 1;
  }

  if (MODE == 0) {
    // per-lane col sums: reduce over the 16 lanes (m) of each quad, then waves via LDS.
    float* sarr = (float*)Xl;   // [4][128]
    float* sqarr = sarr + 512;  // [4][128]
#pragma unroll
    for (int ct = 0; ct < 8; ct++) {
      float4v s = ssum[ct], s2 = ssq[ct];
#pragma unroll
      for (int d = 1; d < 16; d <<= 1) {
#pragma unroll
        for (int j = 0; j < 4; j++) {
          s[j] += __shfl_xor(s[j], d);
          s2[j] += __shfl_xor(s2[j], d);
        }
      }
      if (m == 0) {
        *(float4v*)&sarr[w * 128 + ct * 16 + quad * 4] = s;
        *(float4v*)&sqarr[w * 128 + ct * 16 + quad * 4] = s2;
      }
    }
    __syncthreads();
    if (tid < 128) {
      atomicAdd(&stats[tid], sarr[tid] + sarr[128 + tid] + sarr[256 + tid] + sarr[384 + tid]);
    } else {
      int c = tid - 128;
      atomicAdd(&stats[128 + c], sqarr[c] + sqarr[128 + c] + sqarr[256 + c] + sqarr[384 + c]);
    }
  }
}

// ---------------- driver ----------------
static inline size_t align256(size_t x) { return (x + 255) & ~(size_t)255; }

extern "C" void kernel_launch(void* const* d_in, const int* in_sizes, int n_in,
                              void* d_out, int out_size, void* d_ws, size_t ws_size,
                              hipStream_t stream) {
  const float* x     = (const float*)d_in[0];
  const int*   ei    = (const int*)d_in[1];
  const float* attr  = (const float*)d_in[2];
  const float* We    = (const float*)d_in[3];
  const float* be    = (const float*)d_in[4];
  const float* eps   = (const float*)d_in[5];
  const float* W1    = (const float*)d_in[6];
  const float* b1    = (const float*)d_in[7];
  const float* gamma = (const float*)d_in[8];
  const float* beta  = (const float*)d_in[9];
  const float* W2    = (const float*)d_in[10];
  const float* b2    = (const float*)d_in[11];
  float* out = (float*)d_out;

  char* w = (char*)d_ws;
  unsigned short* z2 = (unsigned short*)w; w += align256((size_t)NN * DD * 2);
  unsigned short* hb = (unsigned short*)w; w += align256((size_t)NN * DD * 2);
  unsigned short* zb = (unsigned short*)w; w += align256((size_t)NN * DD * 2);
  int*   row_ptr  = (int*)w;   w += align256((size_t)(NN + 1) * 4);
  int*   counts   = (int*)w;   w += align256((size_t)NN * 4);
  int*   off      = (int*)w;   w += align256((size_t)NN * 4);
  int2*  csr      = (int2*)w;  w += align256((size_t)NE * 8);
  float* stats4   = (float*)w; w += align256((size_t)NL * 256 * 4);
  int*   bsums    = (int*)w;   w += align256(ST * 4);
  int*   boffs    = (int*)w;   w += align256(ST * 4);
  unsigned short* WTb = (unsigned short*)w; w += align256((size_t)8 * 16384 * 2);

  // weight prep + layer-0 bf16 mirror (also zeroes counts/stats) + CSR build
  k_prep<<<512, 256, 0, stream>>>(W1, W2, WTb);
  k_h2b<<<(NN * DD / 4 + 255) / 256, 256, 0, stream>>>(x, hb, stats4, counts);
  k_count<<<(NE + 255) / 256, 256, 0, stream>>>(ei, counts);
  k_scan_part<<<SB, ST, 0, stream>>>(counts, row_ptr, bsums);
  k_scan_bsum<<<1, ST, 0, stream>>>(bsums, boffs, row_ptr);
  k_scan_add<<<SB, ST, 0, stream>>>(boffs, row_ptr, off);
  k_fill<<<(NE + 255) / 256, 256, 0, stream>>>(ei, attr, row_ptr, off, csr);

  for (int l = 0; l < NL; l++) {
    float* st = stats4 + (size_t)l * 256;
    k_agg<<<(NN * 64 + 255) / 256, 256, 0, stream>>>(
        hb, row_ptr, csr, We + l * DD, be + l * DD, eps + l, zb);
    // z2(bf16) = zb @ W1 + b1, fused stats
    k_gemm<0><<<GB, 256, 0, stream>>>(zb, WTb + (size_t)l * 16384, b1 + l * DD,
                                      st, nullptr, nullptr, nullptr, nullptr, z2);
    unsigned short* hbo = (l < NL - 1) ? hb : nullptr;
    if (l == 0)
      k_gemm<1><<<GB, 256, 0, stream>>>(z2, WTb + (size_t)(4 + l) * 16384, b2 + l * DD,
                                        st, gamma + l * DD, beta + l * DD,
                                        nullptr, out, hbo);
    else
      k_gemm<2><<<GB, 256, 0, stream>>>(z2, WTb + (size_t)(4 + l) * 16384, b2 + l * DD,
                                        st, gamma + l * DD, beta + l * DD,
                                        out, out, hbo);
  }
}

// Round 4
// 532.808 us; speedup vs baseline: 1.4653x; 1.0756x over previous
//
#include <hip/hip_runtime.h>

#define NN 100000
#define NE 600000
#define DD 128
#define NL 4
#define GB 512  // persistent GEMM grid: 2 blocks/CU x 256 CU

typedef __attribute__((ext_vector_type(8))) short short8;
typedef __attribute__((ext_vector_type(4))) float float4v;

__device__ inline unsigned short f2bf(float f) {
  union { float f; unsigned u; } v; v.f = f;
  unsigned r = v.u + 0x7fff + ((v.u >> 16) & 1);  // round-to-nearest-even
  return (unsigned short)(r >> 16);
}
__device__ inline float bf2f(unsigned short u) {
  union { unsigned u; float f; } v; v.u = ((unsigned)u) << 16;
  return v.f;
}

// ---------------- one-time: W1/W2 -> bf16 transposed [n][k]; zero counts/stats ----
__global__ void k_prep(const float* __restrict__ W1, const float* __restrict__ W2,
                       unsigned short* __restrict__ WT, int* __restrict__ counts,
                       float* __restrict__ stats4) {
  int i = blockIdx.x * 256 + threadIdx.x;  // over 8*16384 = 131072
  if (i < NN) counts[i] = 0;
  if (i < NL * 256) stats4[i] = 0.f;
  if (i >= 8 * 16384) return;
  int m = i >> 14;
  int el = i & 16383;
  int k = el >> 7;
  int n = el & 127;
  const float* src = (m < 4) ? (W1 + (size_t)m * 16384) : (W2 + (size_t)(m - 4) * 16384);
  WT[(size_t)m * 16384 + n * 128 + k] = f2bf(src[k * 128 + n]);
}

// -------- setup: fp32 x -> bf16 mirror, fused edge counting (counts pre-zeroed) ----
__global__ void k_h2b(const float* __restrict__ src, unsigned short* __restrict__ dst,
                      const int* __restrict__ ei, int* __restrict__ counts) {
  int i = blockIdx.x * 256 + threadIdx.x;
  if (i < NE) atomicAdd(&counts[ei[NE + i]], 1);
  if (i >= NN * DD / 4) return;
  float4 v = ((const float4*)src)[i];
  ushort4 o;
  o.x = f2bf(v.x); o.y = f2bf(v.y); o.z = f2bf(v.z); o.w = f2bf(v.w);
  ((ushort4*)dst)[i] = o;
}

// ---------------- CSR build (once per call) ----------------
#define ST 256
#define SC 2
#define SB ((NN + ST * SC - 1) / (ST * SC))  // 196 blocks

__global__ void k_scan_part(const int* __restrict__ counts, int* __restrict__ row_ptr,
                            int* __restrict__ bsums) {
  __shared__ int s[ST];
  int b = blockIdx.x, t = threadIdx.x;
  int base = b * (ST * SC) + t * SC;
  int v0 = (base < NN) ? counts[base] : 0;
  int v1 = (base + 1 < NN) ? counts[base + 1] : 0;
  int tsum = v0 + v1;
  s[t] = tsum;
  __syncthreads();
  for (int d = 1; d < ST; d <<= 1) {
    int x = (t >= d) ? s[t - d] : 0;
    __syncthreads();
    s[t] += x;
    __syncthreads();
  }
  int excl = s[t] - tsum;
  if (base < NN) row_ptr[base] = excl;
  if (base + 1 < NN) row_ptr[base + 1] = excl + v0;
  if (t == ST - 1) bsums[b] = s[t];
}

__global__ void k_scan_bsum(const int* __restrict__ bsums, int* __restrict__ boffs,
                            int* __restrict__ row_ptr) {
  __shared__ int s[ST];
  int t = threadIdx.x;
  int v = (t < SB) ? bsums[t] : 0;
  s[t] = v;
  __syncthreads();
  for (int d = 1; d < ST; d <<= 1) {
    int x = (t >= d) ? s[t - d] : 0;
    __syncthreads();
    s[t] += x;
    __syncthreads();
  }
  if (t < SB) boffs[t] = s[t] - v;
  if (t == ST - 1) row_ptr[NN] = s[t];
}

__global__ void k_scan_add(const int* __restrict__ boffs, int* __restrict__ row_ptr,
                           int* __restrict__ off) {
  int b = blockIdx.x, t = threadIdx.x;
  int base = b * (ST * SC) + t * SC;
  int o = boffs[b];
  if (base < NN) { row_ptr[base] += o; off[base] = 0; }
  if (base + 1 < NN) { row_ptr[base + 1] += o; off[base + 1] = 0; }
}

// packed CSR record: .x = src node, .y = attr bits (one 8B store per edge)
__global__ void k_fill(const int* __restrict__ ei, const float* __restrict__ attr,
                       const int* __restrict__ row_ptr, int* __restrict__ off,
                       int2* __restrict__ csr) {
  int e = blockIdx.x * 256 + threadIdx.x;
  if (e >= NE) return;
  int srcv = ei[e];
  int dstv = ei[NE + e];
  int pos = atomicAdd(&off[dstv], 1);
  int idx = row_ptr[dstv] + pos;
  csr[idx] = make_int2(srcv, __float_as_int(attr[e]));
}

// ------- aggregation: zb = bf16( (1+eps)*hb[n] + sum relu(hb[src]+attr*We+be) ) -------
// 16 lanes per node (8 features/lane): each edge gather is a dwordx4 per lane,
// 4 edges per wave-wide VMEM issue -> 4x fewer VMEM instructions and 4x fewer
// waves than the old 64-lane/node shape.  Shuffles are width-16 broadcasts.
#define CONSUME(hv, a)                                                                   \
  do {                                                                                   \
    acc0.x += fmaxf(__uint_as_float((hv).x << 16)          + fmaf((a), we0.x, be0.x), 0.f); \
    acc0.y += fmaxf(__uint_as_float((hv).x & 0xffff0000u)  + fmaf((a), we0.y, be0.y), 0.f); \
    acc0.z += fmaxf(__uint_as_float((hv).y << 16)          + fmaf((a), we0.z, be0.z), 0.f); \
    acc0.w += fmaxf(__uint_as_float((hv).y & 0xffff0000u)  + fmaf((a), we0.w, be0.w), 0.f); \
    acc1.x += fmaxf(__uint_as_float((hv).z << 16)          + fmaf((a), we1.x, be1.x), 0.f); \
    acc1.y += fmaxf(__uint_as_float((hv).z & 0xffff0000u)  + fmaf((a), we1.y, be1.y), 0.f); \
    acc1.z += fmaxf(__uint_as_float((hv).w << 16)          + fmaf((a), we1.z, be1.z), 0.f); \
    acc1.w += fmaxf(__uint_as_float((hv).w & 0xffff0000u)  + fmaf((a), we1.w, be1.w), 0.f); \
  } while (0)

__global__ void k_agg(const unsigned short* __restrict__ hb,
                      const int* __restrict__ row_ptr, const int2* __restrict__ csr,
                      const float* __restrict__ We, const float* __restrict__ be,
                      const float* __restrict__ epsp, unsigned short* __restrict__ zb) {
  int gid = blockIdx.x * blockDim.x + threadIdx.x;
  int n = gid >> 4;
  int li = gid & 15;
  if (n >= NN) return;
  int d0 = li * 8;
  float4 we0 = *(const float4*)(We + d0);
  float4 we1 = *(const float4*)(We + d0 + 4);
  float4 be0 = *(const float4*)(be + d0);
  float4 be1 = *(const float4*)(be + d0 + 4);
  int b = row_ptr[n], e = row_ptr[n + 1];
  int deg = e - b;
  int cnt = (deg < 16) ? deg : 16;
  int2 rec = (li < cnt) ? csr[b + li] : make_int2(0, 0);
  int myidx = rec.x;
  float myatt = __int_as_float(rec.y);

  float4 acc0 = make_float4(0.f, 0.f, 0.f, 0.f);
  float4 acc1 = make_float4(0.f, 0.f, 0.f, 0.f);

  int i = 0;
  for (; i + 4 <= cnt; i += 4) {
    int s0 = __shfl(myidx, i, 16);
    int s1 = __shfl(myidx, i + 1, 16);
    int s2 = __shfl(myidx, i + 2, 16);
    int s3 = __shfl(myidx, i + 3, 16);
    float a0 = __shfl(myatt, i, 16);
    float a1 = __shfl(myatt, i + 1, 16);
    float a2 = __shfl(myatt, i + 2, 16);
    float a3 = __shfl(myatt, i + 3, 16);
    uint4 hv0 = *(const uint4*)(hb + (size_t)s0 * DD + d0);
    uint4 hv1 = *(const uint4*)(hb + (size_t)s1 * DD + d0);
    uint4 hv2 = *(const uint4*)(hb + (size_t)s2 * DD + d0);
    uint4 hv3 = *(const uint4*)(hb + (size_t)s3 * DD + d0);
    CONSUME(hv0, a0);
    CONSUME(hv1, a1);
    CONSUME(hv2, a2);
    CONSUME(hv3, a3);
  }
  for (; i < cnt; i++) {
    int s = __shfl(myidx, i, 16);
    float a = __shfl(myatt, i, 16);
    uint4 hv = *(const uint4*)(hb + (size_t)s * DD + d0);
    CONSUME(hv, a);
  }
  // degree > 16 tail (rare; correctness fallback — broadcast load per edge)
  for (int j = b + 16; j < e; j++) {
    int2 r2 = csr[j];
    float a = __int_as_float(r2.y);
    uint4 hv = *(const uint4*)(hb + (size_t)r2.x * DD + d0);
    CONSUME(hv, a);
  }

  float ep = 1.f + epsp[0];
  uint4 hs = *(const uint4*)(hb + (size_t)n * DD + d0);
  float z0 = fmaf(ep, __uint_as_float(hs.x << 16), acc0.x);
  float z1 = fmaf(ep, __uint_as_float(hs.x & 0xffff0000u), acc0.y);
  float z2 = fmaf(ep, __uint_as_float(hs.y << 16), acc0.z);
  float z3 = fmaf(ep, __uint_as_float(hs.y & 0xffff0000u), acc0.w);
  float z4 = fmaf(ep, __uint_as_float(hs.z << 16), acc1.x);
  float z5 = fmaf(ep, __uint_as_float(hs.z & 0xffff0000u), acc1.y);
  float z6 = fmaf(ep, __uint_as_float(hs.w << 16), acc1.z);
  float z7 = fmaf(ep, __uint_as_float(hs.w & 0xffff0000u), acc1.w);
  uint4 o;
  o.x = (unsigned)f2bf(z0) | ((unsigned)f2bf(z1) << 16);
  o.y = (unsigned)f2bf(z2) | ((unsigned)f2bf(z3) << 16);
  o.z = (unsigned)f2bf(z4) | ((unsigned)f2bf(z5) << 16);
  o.w = (unsigned)f2bf(z6) | ((unsigned)f2bf(z7) << 16);
  *(uint4*)(zb + (size_t)n * DD + d0) = o;
}

// ---------------- persistent double-buffered MFMA bf16 GEMM ----------------
// Operand-swapped (A = W^T tile, B = X rows): each lane owns ONE output row and
// 4 consecutive cols per ct chunk -> float4/dwordx4 epilogue.
// MODE 0: z2(bf16) = Xb@W + b, fused column stats (sum,sumsq) -> stats[256]
// MODE 1: Y = relu( relu(bn(Xb))@W + b );       Ybf = bf16(Y) if non-null
// MODE 2: Y = hprev + relu( relu(bn(Xb))@W + b ); same mirror (hprev==Y safe)
// MODE 1/2 compute BN scale/shift from stats+gamma+beta in-kernel (per block).
template <int MODE>
__global__ __launch_bounds__(256, 2) void k_gemm(
    const unsigned short* __restrict__ Xb, const unsigned short* __restrict__ WT,
    const float* __restrict__ bias, float* __restrict__ stats,
    const float* __restrict__ gamma, const float* __restrict__ beta,
    const float* __restrict__ hprev, float* __restrict__ Yout,
    unsigned short* __restrict__ Ybf) {
  __shared__ unsigned short Wl[128 * 136];     // 34816 B
  __shared__ unsigned short Xl[2][64 * 136];   // 2 x 17408 B
  __shared__ float bns[256];                   // 1024 B -> total 70656 B, 2 blk/CU
  const int tid = threadIdx.x;
  const int G = gridDim.x;
  const int NT = (NN + 63) >> 6;  // 1563

  // stage W^T bf16 [n][k] -> LDS, once per block
  for (int i = tid; i < 2048; i += 256) {
    int rr = i >> 4, c = i & 15;
    *(uint4*)&Wl[rr * 136 + c * 8] = *(const uint4*)&WT[rr * 128 + c * 8];
  }

  const int lane = tid & 63;
  const int w = tid >> 6;
  const int m = lane & 15;
  const int quad = lane >> 4;

  // staging mapping: 16B bf16 chunks; c8 = chunk, rows rr16 + it*16
  const int c8 = tid & 15, rr16 = tid >> 4;
  float scl[8], sfl[8];
  if (MODE >= 1) {
    if (tid < 128) {
      const float invN = 1.f / (float)NN;
      float mu = stats[tid] * invN;
      float var = fmaxf(stats[128 + tid] * invN - mu * mu, 0.f);
      float xx = var + 1e-5f;
      float r = rsqrtf(xx);
      r = r * (1.5f - 0.5f * xx * r * r);  // Newton step
      float scale = gamma[tid] * r;
      bns[tid] = scale;
      bns[128 + tid] = beta[tid] - mu * scale;
    }
    __syncthreads();
#pragma unroll
    for (int j = 0; j < 8; j++) {
      scl[j] = bns[c8 * 8 + j];
      sfl[j] = bns[128 + c8 * 8 + j];
    }
  }

  uint4 xu[4];  // prefetch regs (8 bf16 each)
  auto LOADR = [&](int t) {
    int r0 = t << 6;
#pragma unroll
    for (int it = 0; it < 4; it++) {
      int gr = r0 + rr16 + it * 16;
      xu[it] = (gr < NN) ? *(const uint4*)(Xb + (size_t)gr * DD + c8 * 8)
                         : make_uint4(0u, 0u, 0u, 0u);
    }
  };
  auto STORE_LDS = [&](int b) {
#pragma unroll
    for (int it = 0; it < 4; it++) {
      int row = rr16 + it * 16;
      uint4 u = xu[it];
      if (MODE >= 1) {
        unsigned p[4] = {u.x, u.y, u.z, u.w};
#pragma unroll
        for (int j = 0; j < 4; j++) {
          float lo = bf2f((unsigned short)(p[j] & 0xffffu));
          float hi = bf2f((unsigned short)(p[j] >> 16));
          lo = fmaxf(fmaf(lo, scl[2 * j], sfl[2 * j]), 0.f);
          hi = fmaxf(fmaf(hi, scl[2 * j + 1], sfl[2 * j + 1]), 0.f);
          p[j] = (unsigned)f2bf(lo) | ((unsigned)f2bf(hi) << 16);
        }
        u = make_uint4(p[0], p[1], p[2], p[3]);
      }
      *(uint4*)&Xl[b][row * 136 + c8 * 8] = u;
    }
  };

  float4v ssum[8], ssq[8];
  if (MODE == 0) {
#pragma unroll
    for (int ct = 0; ct < 8; ct++) {
      ssum[ct] = (float4v){0.f, 0.f, 0.f, 0.f};
      ssq[ct] = (float4v){0.f, 0.f, 0.f, 0.f};
    }
  }

  const int t0 = blockIdx.x;
  LOADR(t0);
  STORE_LDS(0);
  if (t0 + G < NT) LOADR(t0 + G);
  __syncthreads();  // Xl[0] + Wl ready

  int buf = 0;
  for (int t = t0; t < NT; t += G) {
    const int nxt = t + G;
    if (nxt < NT) {
      STORE_LDS(buf ^ 1);                 // regs hold tile nxt (loaded last iter)
      if (nxt + G < NT) LOADR(nxt + G);   // prefetch tile nxt+G
    }

    float4v acc[8];
#pragma unroll
    for (int ct = 0; ct < 8; ct++) {
      float4 b4 = *(const float4*)&bias[ct * 16 + quad * 4];
      acc[ct] = (float4v){b4.x, b4.y, b4.z, b4.w};
    }

    // A = W^T rows (output cols), B = X rows (output rows in lanes)
    const unsigned short* Ap = &Wl[m * 136 + quad * 8];
    const unsigned short* Bp = &Xl[buf][(w * 16 + m) * 136 + quad * 8];
#pragma unroll
    for (int q = 0; q < 4; q++) {
      short8 bfrag = *(const short8*)(Bp + q * 32);
#pragma unroll
      for (int ct = 0; ct < 8; ct++) {
        short8 afrag = *(const short8*)(Ap + ct * 16 * 136 + q * 32);
        acc[ct] = __builtin_amdgcn_mfma_f32_16x16x32_bf16(afrag, bfrag, acc[ct], 0, 0, 0);
      }
    }

    // LDS-only fence; epilogue global stores stay in flight across tiles.
    asm volatile("s_waitcnt lgkmcnt(0)" ::: "memory");
    __builtin_amdgcn_s_barrier();

    const int r = (t << 6) + w * 16 + m;  // this lane's output row
    if (r < NN) {
      const size_t rb = (size_t)r * DD;
#pragma unroll
      for (int ct = 0; ct < 8; ct++) {
        float4v v = acc[ct];
        const int col = ct * 16 + quad * 4;
        if (MODE == 0) {
          ssum[ct] += v;
          ssq[ct] += v * v;
          ushort4 o;
          o.x = f2bf(v[0]); o.y = f2bf(v[1]); o.z = f2bf(v[2]); o.w = f2bf(v[3]);
          *(ushort4*)&Ybf[rb + col] = o;
        } else {
          v[0] = fmaxf(v[0], 0.f); v[1] = fmaxf(v[1], 0.f);
          v[2] = fmaxf(v[2], 0.f); v[3] = fmaxf(v[3], 0.f);
          if (MODE == 2) {
            float4 hp = *(const float4*)&hprev[rb + col];
            v[0] += hp.x; v[1] += hp.y; v[2] += hp.z; v[3] += hp.w;
          }
          *(float4v*)&Yout[rb + col] = v;
          if (Ybf) {
            ushort4 o;
            o.x = f2bf(v[0]); o.y = f2bf(v[1]); o.z = f2bf(v[2]); o.w = f2bf(v[3]);
            *(ushort4*)&Ybf[rb + col] = o;
          }
        }
      }
    }
    buf ^= 1;
  }

  if (MODE == 0) {
    // per-lane col sums: reduce over the 16 lanes (m) of each quad, then waves via LDS.
    float* sarr = (float*)Xl;   // [4][128]
    float* sqarr = sarr + 512;  // [4][128]
#pragma unroll
    for (int ct = 0; ct < 8; ct++) {
      float4v s = ssum[ct], s2 = ssq[ct];
#pragma unroll
      for (int d = 1; d < 16; d <<= 1) {
#pragma unroll
        for (int j = 0; j < 4; j++) {
          s[j] += __shfl_xor(s[j], d);
          s2[j] += __shfl_xor(s2[j], d);
        }
      }
      if (m == 0) {
        *(float4v*)&sarr[w * 128 + ct * 16 + quad * 4] = s;
        *(float4v*)&sqarr[w * 128 + ct * 16 + quad * 4] = s2;
      }
    }
    __syncthreads();
    if (tid < 128) {
      atomicAdd(&stats[tid], sarr[tid] + sarr[128 + tid] + sarr[256 + tid] + sarr[384 + tid]);
    } else {
      int c = tid - 128;
      atomicAdd(&stats[128 + c], sqarr[c] + sqarr[128 + c] + sqarr[256 + c] + sqarr[384 + c]);
    }
  }
}

// ---------------- driver ----------------
static inline size_t align256(size_t x) { return (x + 255) & ~(size_t)255; }

extern "C" void kernel_launch(void* const* d_in, const int* in_sizes, int n_in,
                              void* d_out, int out_size, void* d_ws, size_t ws_size,
                              hipStream_t stream) {
  const float* x     = (const float*)d_in[0];
  const int*   ei    = (const int*)d_in[1];
  const float* attr  = (const float*)d_in[2];
  const float* We    = (const float*)d_in[3];
  const float* be    = (const float*)d_in[4];
  const float* eps   = (const float*)d_in[5];
  const float* W1    = (const float*)d_in[6];
  const float* b1    = (const float*)d_in[7];
  const float* gamma = (const float*)d_in[8];
  const float* beta  = (const float*)d_in[9];
  const float* W2    = (const float*)d_in[10];
  const float* b2    = (const float*)d_in[11];
  float* out = (float*)d_out;

  char* w = (char*)d_ws;
  unsigned short* z2 = (unsigned short*)w; w += align256((size_t)NN * DD * 2);
  unsigned short* hb = (unsigned short*)w; w += align256((size_t)NN * DD * 2);
  unsigned short* zb = (unsigned short*)w; w += align256((size_t)NN * DD * 2);
  int*   row_ptr  = (int*)w;   w += align256((size_t)(NN + 1) * 4);
  int*   counts   = (int*)w;   w += align256((size_t)NN * 4);
  int*   off      = (int*)w;   w += align256((size_t)NN * 4);
  int2*  csr      = (int2*)w;  w += align256((size_t)NE * 8);
  float* stats4   = (float*)w; w += align256((size_t)NL * 256 * 4);
  int*   bsums    = (int*)w;   w += align256(ST * 4);
  int*   boffs    = (int*)w;   w += align256(ST * 4);
  unsigned short* WTb = (unsigned short*)w; w += align256((size_t)8 * 16384 * 2);

  // weight prep (zeroes counts+stats) -> h2b (fused edge count) -> CSR build
  k_prep<<<512, 256, 0, stream>>>(W1, W2, WTb, counts, stats4);
  k_h2b<<<(NN * DD / 4 + 255) / 256, 256, 0, stream>>>(x, hb, ei, counts);
  k_scan_part<<<SB, ST, 0, stream>>>(counts, row_ptr, bsums);
  k_scan_bsum<<<1, ST, 0, stream>>>(bsums, boffs, row_ptr);
  k_scan_add<<<SB, ST, 0, stream>>>(boffs, row_ptr, off);
  k_fill<<<(NE + 255) / 256, 256, 0, stream>>>(ei, attr, row_ptr, off, csr);

  for (int l = 0; l < NL; l++) {
    float* st = stats4 + (size_t)l * 256;
    k_agg<<<(NN * 16 + 255) / 256, 256, 0, stream>>>(
        hb, row_ptr, csr, We + l * DD, be + l * DD, eps + l, zb);
    // z2(bf16) = zb @ W1 + b1, fused stats
    k_gemm<0><<<GB, 256, 0, stream>>>(zb, WTb + (size_t)l * 16384, b1 + l * DD,
                                      st, nullptr, nullptr, nullptr, nullptr, z2);
    unsigned short* hbo = (l < NL - 1) ? hb : nullptr;
    if (l == 0)
      k_gemm<1><<<GB, 256, 0, stream>>>(z2, WTb + (size_t)(4 + l) * 16384, b2 + l * DD,
                                        st, gamma + l * DD, beta + l * DD,
                                        nullptr, out, hbo);
    else
      k_gemm<2><<<GB, 256, 0, stream>>>(z2, WTb + (size_t)(4 + l) * 16384, b2 + l * DD,
                                        st, gamma + l * DD, beta + l * DD,
                                        out, out, hbo);
  }
}